// Round 1
// baseline (241.232 us; speedup 1.0000x reference)
//
#include <hip/hip_runtime.h>
#include <hip/hip_bf16.h>

// HMM forward-backward posterior marginals, N=16384 steps, S=512 states.
// Strategy: chunked parallel scan with warmup (mixing makes warmup error
// ~0.04^W relative); per-timestep scale factors cancel in gamma so fwd and
// bwd run concurrently, unnormalized; per-step batched matvec = bf16 MFMA GEMM.

typedef __bf16 bf16_t;
typedef bf16_t bf16x8 __attribute__((ext_vector_type(8)));
typedef float  floatx4 __attribute__((ext_vector_type(4)));

#define N_T   16384
#define S_DIM 512
#define LCH   4                 // chunk length (stored timesteps per chain)
#define WARM  4                 // warmup steps before first store
#define NLOC  (WARM + LCH)      // local steps: s=0 init + s=1..7 GEMM steps
#define MBLK  32                // chains per workgroup
#define WGDIR 128               // (N_T/LCH)/MBLK workgroups per direction
#define PITCH 520               // LDS row pitch (bf16 elems); +8 breaks bank conflicts

// workspace layout (bytes); total 51,380,224
#define OBSB_OFF   ((size_t)0)          // obs bf16: 16,777,216
#define ALPHA_OFF  ((size_t)16777216)   // alphas bf16: 16,777,216
#define BETA_OFF   ((size_t)33554432)   // betas bf16: 16,777,216
#define PACKF_OFF  ((size_t)50331648)   // packed A (fwd B-operand): 524,288
#define PACKB_OFF  ((size_t)50855936)   // packed A^T (bwd B-operand): 524,288

__global__ __launch_bounds__(256) void prep_obs_k(const float* __restrict__ src,
                                                  bf16_t* __restrict__ dst) {
    int i = blockIdx.x * 256 + threadIdx.x;   // 1,048,576 threads x 8 elems
    const float4* s4 = (const float4*)src;
    float4 a = s4[(size_t)i * 2], b = s4[(size_t)i * 2 + 1];
    bf16x8 o;
    o[0] = (bf16_t)a.x; o[1] = (bf16_t)a.y; o[2] = (bf16_t)a.z; o[3] = (bf16_t)a.w;
    o[4] = (bf16_t)b.x; o[5] = (bf16_t)b.y; o[6] = (bf16_t)b.z; o[7] = (bf16_t)b.w;
    *(bf16x8*)(dst + (size_t)i * 8) = o;
}

// pack[kb][n][i] = M[kb*8+i][n]  (M = A for fwd, A^T for bwd)
// -> MFMA 16x16x32 B-fragment: lane l loads 16B at ((k0/8 + (l>>4))*512 + n0 + (l&15))*8
__global__ __launch_bounds__(256) void prep_pack_k(const float* __restrict__ A,
                                                   bf16_t* __restrict__ pf,
                                                   bf16_t* __restrict__ pb) {
    int idx = blockIdx.x * 256 + threadIdx.x;  // 32768 = 64 kb * 512 n
    int kb = idx >> 9, n = idx & 511;
    bf16x8 f, b;
    #pragma unroll
    for (int i = 0; i < 8; ++i) {
        f[i] = (bf16_t)A[(size_t)(kb * 8 + i) * 512 + n];   // A[k][n]
        b[i] = (bf16_t)A[(size_t)n * 512 + kb * 8 + i];     // A^T[k][n] = A[n][k]
    }
    *(bf16x8*)(pf + (size_t)idx * 8) = f;
    *(bf16x8*)(pb + (size_t)idx * 8) = b;
}

__global__ __launch_bounds__(256) void hmm_main_k(
    const bf16_t* __restrict__ obs,
    const bf16_t* __restrict__ packF,
    const bf16_t* __restrict__ packB,
    const float*  __restrict__ pi0,
    bf16_t* __restrict__ alphas,
    bf16_t* __restrict__ betas)
{
    __shared__ __align__(16) bf16_t Xs[MBLK][PITCH];
    const int tid = threadIdx.x;
    const bool bwd = blockIdx.x >= WGDIR;
    const int wgi = bwd ? blockIdx.x - WGDIR : blockIdx.x;
    const int c0 = wgi * MBLK;
    const bf16_t* pack = bwd ? packB : packF;

    const int mrow = tid >> 3;          // 8 threads per row
    const int j0 = (tid & 7) * 64;      // 64 contiguous elems per thread

    // ---- s = 0: init X rows with obs[t_start] (arbitrary positive init is
    // fine for warmup chains; exact cases re-initialized at their real t). ----
    {
        int c = c0 + mrow;
        int t = bwd ? (c * LCH + LCH - 1 + WARM) : (c * LCH - WARM);
        int tcl = t < 0 ? 0 : (t > N_T - 1 ? N_T - 1 : t);
        const bf16_t* ob = obs + (size_t)tcl * S_DIM + j0;
        #pragma unroll
        for (int u = 0; u < 8; ++u)
            *(bf16x8*)&Xs[mrow][j0 + u * 8] = *(const bf16x8*)(ob + u * 8);
    }
    __syncthreads();

    const int lane = tid & 63;
    const int wv = tid >> 6;
    const int lm = lane & 15;
    const int q  = lane >> 4;
    const int ncol0 = wv * 128;         // each wave owns 128 output columns

    const bf16_t* xb0 = &Xs[0  + lm][q * 8];
    const bf16_t* xb1 = &Xs[16 + lm][q * 8];
    const bf16_t* pb0 = pack + ((size_t)q * 512 + ncol0 + lm) * 8;

    for (int s = 1; s < NLOC; ++s) {
        // ---- GEMM: acc[mt][nt] = X @ pack  (X is [32 x 512] bf16 in LDS) ----
        floatx4 acc[2][8];
        #pragma unroll
        for (int mt = 0; mt < 2; ++mt)
            #pragma unroll
            for (int nt = 0; nt < 8; ++nt)
                acc[mt][nt] = (floatx4){0.f, 0.f, 0.f, 0.f};
        #pragma unroll 4
        for (int kk = 0; kk < 16; ++kk) {
            bf16x8 a0 = *(const bf16x8*)(xb0 + kk * 32);
            bf16x8 a1 = *(const bf16x8*)(xb1 + kk * 32);
            const bf16_t* bp = pb0 + (size_t)kk * (4 * 512 * 8);
            #pragma unroll
            for (int nt = 0; nt < 8; ++nt) {
                bf16x8 bfr = *(const bf16x8*)(bp + nt * 128);
                acc[0][nt] = __builtin_amdgcn_mfma_f32_16x16x32_bf16(a0, bfr, acc[0][nt], 0, 0, 0);
                acc[1][nt] = __builtin_amdgcn_mfma_f32_16x16x32_bf16(a1, bfr, acc[1][nt], 0, 0, 0);
            }
        }
        __syncthreads();   // all waves done reading Xs
        // ---- write raw GEMM result back to LDS (C/D: row=q*4+r, col=lm) ----
        #pragma unroll
        for (int mt = 0; mt < 2; ++mt)
            #pragma unroll
            for (int nt = 0; nt < 8; ++nt)
                #pragma unroll
                for (int r = 0; r < 4; ++r)
                    Xs[mt * 16 + q * 4 + r][ncol0 + nt * 16 + lm] = (bf16_t)acc[mt][nt][r];
        __syncthreads();
        // ---- obs multiply (+ exact re-init) + store phase ----
        {
            int c = c0 + mrow;
            int t = bwd ? (c * LCH + LCH - 1 + WARM - s) : (c * LCH - WARM + s);
            int tcl = t < 0 ? 0 : (t > N_T - 1 ? N_T - 1 : t);
            const bf16_t* ob = obs + (size_t)tcl * S_DIM + j0;
            const bool store = (s >= WARM);   // t inside chunk <=> s >= WARM
            if (!bwd) {
                // alpha_t = (alpha_{t-1} @ A) * obs[t]; chunk0/t0: pi0*obs[0] exact
                const bool isinit = (c == 0) && (t == 0);
                #pragma unroll
                for (int u = 0; u < 8; ++u) {
                    bf16x8 x = *(bf16x8*)&Xs[mrow][j0 + u * 8];
                    bf16x8 o = *(const bf16x8*)(ob + u * 8);
                    bf16x8 y;
                    #pragma unroll
                    for (int e = 0; e < 8; ++e) {
                        float v = isinit ? pi0[j0 + u * 8 + e] : (float)x[e];
                        y[e] = (bf16_t)(v * (float)o[e]);
                    }
                    *(bf16x8*)&Xs[mrow][j0 + u * 8] = y;
                    if (store) *(bf16x8*)(alphas + (size_t)t * S_DIM + j0 + u * 8) = y;
                }
            } else {
                // beta_t = A @ (beta_{t+1} * obs[t+1]); LDS holds beta_t*obs[t]
                // for the next step; raw beta_t is what we store. t==N-1: ones (exact).
                const bool isinit = (t == N_T - 1);
                #pragma unroll
                for (int u = 0; u < 8; ++u) {
                    bf16x8 x = *(bf16x8*)&Xs[mrow][j0 + u * 8];
                    bf16x8 o = *(const bf16x8*)(ob + u * 8);
                    bf16x8 y, braw;
                    #pragma unroll
                    for (int e = 0; e < 8; ++e) {
                        float v = isinit ? 1.0f : (float)x[e];
                        braw[e] = (bf16_t)v;
                        y[e] = (bf16_t)(v * (float)o[e]);
                    }
                    *(bf16x8*)&Xs[mrow][j0 + u * 8] = y;
                    if (store) *(bf16x8*)(betas + (size_t)t * S_DIM + j0 + u * 8) = braw;
                }
            }
        }
        __syncthreads();
    }
}

__global__ __launch_bounds__(256) void gamma_k(const bf16_t* __restrict__ alphas,
                                               const bf16_t* __restrict__ betas,
                                               float* __restrict__ out)
{
    int row = blockIdx.x * 4 + (threadIdx.x >> 6);   // one wave per timestep
    int lane = threadIdx.x & 63;
    size_t off = (size_t)row * S_DIM + lane * 8;
    bf16x8 a = *(const bf16x8*)(alphas + off);
    bf16x8 b = *(const bf16x8*)(betas + off);
    float p[8]; float sum = 0.f;
    #pragma unroll
    for (int e = 0; e < 8; ++e) { p[e] = (float)a[e] * (float)b[e]; sum += p[e]; }
    #pragma unroll
    for (int d = 1; d < 64; d <<= 1) sum += __shfl_xor(sum, d, 64);
    float inv = 1.0f / sum;
    floatx4 g0 = {p[0] * inv, p[1] * inv, p[2] * inv, p[3] * inv};
    floatx4 g1 = {p[4] * inv, p[5] * inv, p[6] * inv, p[7] * inv};
    *(floatx4*)(out + off) = g0;
    *(floatx4*)(out + off + 4) = g1;
}

extern "C" void kernel_launch(void* const* d_in, const int* in_sizes, int n_in,
                              void* d_out, int out_size, void* d_ws, size_t ws_size,
                              hipStream_t stream)
{
    const float* obs_f = (const float*)d_in[0];   // [16384, 512]
    const float* A     = (const float*)d_in[1];   // [512, 512]
    const float* pi0   = (const float*)d_in[2];   // [512]
    float* out = (float*)d_out;                   // [16384, 512] fp32
    char* ws = (char*)d_ws;
    bf16_t* obs_b  = (bf16_t*)(ws + OBSB_OFF);
    bf16_t* alphas = (bf16_t*)(ws + ALPHA_OFF);
    bf16_t* betas  = (bf16_t*)(ws + BETA_OFF);
    bf16_t* packF  = (bf16_t*)(ws + PACKF_OFF);
    bf16_t* packB  = (bf16_t*)(ws + PACKB_OFF);

    hipLaunchKernelGGL(prep_obs_k,  dim3(4096), dim3(256), 0, stream, obs_f, obs_b);
    hipLaunchKernelGGL(prep_pack_k, dim3(128),  dim3(256), 0, stream, A, packF, packB);
    hipLaunchKernelGGL(hmm_main_k,  dim3(2 * WGDIR), dim3(256), 0, stream,
                       obs_b, packF, packB, pi0, alphas, betas);
    hipLaunchKernelGGL(gamma_k, dim3(N_T / 4), dim3(256), 0, stream, alphas, betas, out);
}